// Round 1
// baseline (71.182 us; speedup 1.0000x reference)
//
#include <hip/hip_runtime.h>

// Closed-form reduction:
//   s = A @ x  (A: [5000,20], x: [20])
//   loss = sum_{i,j} (s_i - b_j)^2
//        = N * sum(s^2) - 2 * sum(s) * sum(b) + N * sum(b^2),  N = 5000
//
// R4 structure: ONE plain dispatch (21 blocks).
//   Blocks 0..19: one row/thread, float4 row loads, x via uniform scalar
//       loads, per-block partials (S1,S2,B1,B2) reduced via wave shuffle +
//       LDS, then published to ws as (value, ~value) bit-complement pairs
//       with agent-scope stores (poison-proof: no pattern P has P == ~P,
//       so the harness's ws re-poison can never fake a completed flag).
//   Block 20: spins (agent-scope loads) until all 20x4 pairs match,
//       acquire-fences, reduces the 20 quadruples, emits the scalar.
//   Deadlock-free: workers never wait; 21 blocks << 256 CUs so all are
//   co-resident and the spinner cannot starve the workers.
// History: two-dispatch version = 58.9 us (fill = 39.7 us of it);
//   cooperative launch regressed ~20 us; single 1024-thread block ~3 us
//   slower (one CU streaming 420 KB of poison-evicted A is latency-bound).

#define N_ROWS 5000
#define N_FEAT 20
#define NBLK   20
#define BLKSZ  256
#define NWAVES (BLKSZ / 64)

typedef unsigned long long u64;

__device__ __forceinline__ double wave_reduce_sum(double v) {
    #pragma unroll
    for (int off = 32; off > 0; off >>= 1)
        v += __shfl_down(v, off, 64);
    return v;
}

__device__ __forceinline__ u64 d2u(double d) { return __double_as_longlong(d); }
__device__ __forceinline__ double u2d(u64 u) { return __longlong_as_double(u); }

__global__ __launch_bounds__(BLKSZ) void lsq_fused_kernel(
        const float* __restrict__ A, const float* __restrict__ b,
        const float* __restrict__ x, u64* __restrict__ ws,
        float* __restrict__ out) {
    if (blockIdx.x < NBLK) {
        // ---------------- worker block: partial sums over 256 rows --------
        double s1 = 0.0, s2 = 0.0, b1 = 0.0, b2 = 0.0;
        int i = blockIdx.x * BLKSZ + threadIdx.x;   // 5120 threads >= 5000 rows
        if (i < N_ROWS) {
            const float4* __restrict__ row = (const float4*)(A + (long)i * N_FEAT);
            float4 r0 = row[0], r1 = row[1], r2 = row[2], r3 = row[3], r4 = row[4];
            float bv = b[i];
            // x is wave-uniform -> compiler emits s_load, no LDS/sync needed
            float s = r0.x * x[0]  + r0.y * x[1]  + r0.z * x[2]  + r0.w * x[3]
                    + r1.x * x[4]  + r1.y * x[5]  + r1.z * x[6]  + r1.w * x[7]
                    + r2.x * x[8]  + r2.y * x[9]  + r2.z * x[10] + r2.w * x[11]
                    + r3.x * x[12] + r3.y * x[13] + r3.z * x[14] + r3.w * x[15]
                    + r4.x * x[16] + r4.y * x[17] + r4.z * x[18] + r4.w * x[19];
            s1 = (double)s;
            s2 = (double)s * (double)s;
            b1 = (double)bv;
            b2 = (double)bv * (double)bv;
        }

        s1 = wave_reduce_sum(s1);
        s2 = wave_reduce_sum(s2);
        b1 = wave_reduce_sum(b1);
        b2 = wave_reduce_sum(b2);

        __shared__ double red[NWAVES][4];
        int lane = threadIdx.x & 63;
        int wave = threadIdx.x >> 6;
        if (lane == 0) {
            red[wave][0] = s1; red[wave][1] = s2;
            red[wave][2] = b1; red[wave][3] = b2;
        }
        __syncthreads();
        if (threadIdx.x == 0) {
            double t0 = 0, t1 = 0, t2 = 0, t3 = 0;
            #pragma unroll
            for (int w = 0; w < NWAVES; ++w) {
                t0 += red[w][0]; t1 += red[w][1];
                t2 += red[w][2]; t3 += red[w][3];
            }
            u64* p = ws + 8 * (u64)blockIdx.x;
            u64 v0 = d2u(t0), v1 = d2u(t1), v2 = d2u(t2), v3 = d2u(t3);
            __hip_atomic_store(&p[0], v0, __ATOMIC_RELAXED, __HIP_MEMORY_SCOPE_AGENT);
            __hip_atomic_store(&p[1], v1, __ATOMIC_RELAXED, __HIP_MEMORY_SCOPE_AGENT);
            __hip_atomic_store(&p[2], v2, __ATOMIC_RELAXED, __HIP_MEMORY_SCOPE_AGENT);
            __hip_atomic_store(&p[3], v3, __ATOMIC_RELAXED, __HIP_MEMORY_SCOPE_AGENT);
            __threadfence();   // release: values visible before sentinels
            __hip_atomic_store(&p[4], ~v0, __ATOMIC_RELAXED, __HIP_MEMORY_SCOPE_AGENT);
            __hip_atomic_store(&p[5], ~v1, __ATOMIC_RELAXED, __HIP_MEMORY_SCOPE_AGENT);
            __hip_atomic_store(&p[6], ~v2, __ATOMIC_RELAXED, __HIP_MEMORY_SCOPE_AGENT);
            __hip_atomic_store(&p[7], ~v3, __ATOMIC_RELAXED, __HIP_MEMORY_SCOPE_AGENT);
        }
    } else {
        // ---------------- finalize block: spin, reduce, emit --------------
        if (threadIdx.x == 0) {
            bool done;
            do {
                done = true;
                for (int blk = 0; blk < NBLK && done; ++blk) {
                    const u64* p = ws + 8 * (u64)blk;
                    #pragma unroll
                    for (int k = 0; k < 4; ++k) {
                        u64 v = __hip_atomic_load(&p[k],     __ATOMIC_RELAXED, __HIP_MEMORY_SCOPE_AGENT);
                        u64 c = __hip_atomic_load(&p[4 + k], __ATOMIC_RELAXED, __HIP_MEMORY_SCOPE_AGENT);
                        if (c != ~v) { done = false; break; }
                    }
                }
                if (!done) __builtin_amdgcn_s_sleep(1);
            } while (!done);
            __threadfence();   // acquire: order spin before value reloads
        }
        __syncthreads();       // broadcast "all published" to the block

        double s1 = 0, s2 = 0, b1 = 0, b2 = 0;
        if (threadIdx.x < NBLK) {
            const u64* p = ws + 8 * (u64)threadIdx.x;
            s1 = u2d(__hip_atomic_load(&p[0], __ATOMIC_RELAXED, __HIP_MEMORY_SCOPE_AGENT));
            s2 = u2d(__hip_atomic_load(&p[1], __ATOMIC_RELAXED, __HIP_MEMORY_SCOPE_AGENT));
            b1 = u2d(__hip_atomic_load(&p[2], __ATOMIC_RELAXED, __HIP_MEMORY_SCOPE_AGENT));
            b2 = u2d(__hip_atomic_load(&p[3], __ATOMIC_RELAXED, __HIP_MEMORY_SCOPE_AGENT));
        }
        // only wave 0 holds nonzero lanes (NBLK=20 < 64); other waves reduce zeros
        s1 = wave_reduce_sum(s1);
        s2 = wave_reduce_sum(s2);
        b1 = wave_reduce_sum(b1);
        b2 = wave_reduce_sum(b2);
        if (threadIdx.x == 0) {
            double n = (double)N_ROWS;
            out[0] = (float)(n * s2 - 2.0 * s1 * b1 + n * b2);
        }
    }
}

extern "C" void kernel_launch(void* const* d_in, const int* in_sizes, int n_in,
                              void* d_out, int out_size, void* d_ws, size_t ws_size,
                              hipStream_t stream) {
    const float* A = (const float*)d_in[0];   // [5000,20]
    const float* b = (const float*)d_in[1];   // [5000]
    const float* x = (const float*)d_in[2];   // [20]
    float* out = (float*)d_out;
    u64* ws = (u64*)d_ws;                     // 21 blocks use 20*8 u64 = 1280 B

    lsq_fused_kernel<<<NBLK + 1, BLKSZ, 0, stream>>>(A, b, x, ws, out);
}

// Round 3
// 58.339 us; speedup vs baseline: 1.2201x; 1.2201x over previous
//
#include <hip/hip_runtime.h>

// Closed-form reduction:
//   s = A @ x  (A: [5000,20], x: [20])
//   loss = sum_{i,j} (s_i - b_j)^2
//        = N * sum(s^2) - 2 * sum(s) * sum(b) + N * sum(b^2),  N = 5000
//
// R5 structure (resubmit — R2 bench was a GPUAcquisitionTimeout, never ran):
//   ONE dispatch, 20 blocks, NO spinner ("poll-once" fusion).
//   Each block: one row/thread, float4 row loads, x via uniform s_loads,
//     partials (S1,S2,B1,B2) via wave shuffle + LDS; thread 0 publishes the
//     4 partials to ws as (value, ~value) pairs with agent-scope stores.
//   The pair check is SELF-VALIDATING vs the harness ws-poison: c == ~v can
//     only hold if v is the true value (no pattern P satisfies P == ~P, and
//     ~value == ~poison forces value == poison).
//   Then wave 0 of EVERY block polls exactly once (lane t<20 checks block
//     t's 4 pairs, __all across the wave). The real-time-last publisher is
//     guaranteed to see all 20 publishes (its fence completed last), so at
//     least one block finalizes; blocks that miss simply exit — no waiting,
//     no deadlock possible. Multiple finalizers write bit-identical doubles
//     to out[0] (same inputs, same reduction order) — benign duplicate.
// History: R1 two-dispatch = 58.9 us (ws-poison fill = 40 us of window);
//   R4 dedicated-spinner fusion = 71.2 us (serial 160-load poll + s_sleep
//   chain after last worker >> saved launch) — REVERTED to poll-once.
//   Cooperative launch −20 us regression; single-block −3 us.

#define N_ROWS 5000
#define N_FEAT 20
#define NBLK   20
#define BLKSZ  256
#define NWAVES (BLKSZ / 64)

typedef unsigned long long u64;

__device__ __forceinline__ double wave_reduce_sum(double v) {
    #pragma unroll
    for (int off = 32; off > 0; off >>= 1)
        v += __shfl_down(v, off, 64);
    return v;
}

__device__ __forceinline__ u64 d2u(double d) { return __double_as_longlong(d); }
__device__ __forceinline__ double u2d(u64 u) { return __longlong_as_double(u); }

__device__ __forceinline__ u64 aload(const u64* p) {
    return __hip_atomic_load(p, __ATOMIC_RELAXED, __HIP_MEMORY_SCOPE_AGENT);
}
__device__ __forceinline__ void astore(u64* p, u64 v) {
    __hip_atomic_store(p, v, __ATOMIC_RELAXED, __HIP_MEMORY_SCOPE_AGENT);
}

__global__ __launch_bounds__(BLKSZ) void lsq_fused_kernel(
        const float* __restrict__ A, const float* __restrict__ b,
        const float* __restrict__ x, u64* __restrict__ ws,
        float* __restrict__ out) {
    // ---------------- per-block partial sums over 256 rows ----------------
    double s1 = 0.0, s2 = 0.0, b1 = 0.0, b2 = 0.0;
    int i = blockIdx.x * BLKSZ + threadIdx.x;   // 5120 threads >= 5000 rows
    if (i < N_ROWS) {
        const float4* __restrict__ row = (const float4*)(A + (long)i * N_FEAT);
        float4 r0 = row[0], r1 = row[1], r2 = row[2], r3 = row[3], r4 = row[4];
        float bv = b[i];
        // x is wave-uniform -> compiler emits s_load, no LDS/sync needed
        float s = r0.x * x[0]  + r0.y * x[1]  + r0.z * x[2]  + r0.w * x[3]
                + r1.x * x[4]  + r1.y * x[5]  + r1.z * x[6]  + r1.w * x[7]
                + r2.x * x[8]  + r2.y * x[9]  + r2.z * x[10] + r2.w * x[11]
                + r3.x * x[12] + r3.y * x[13] + r3.z * x[14] + r3.w * x[15]
                + r4.x * x[16] + r4.y * x[17] + r4.z * x[18] + r4.w * x[19];
        s1 = (double)s;
        s2 = (double)s * (double)s;
        b1 = (double)bv;
        b2 = (double)bv * (double)bv;
    }

    s1 = wave_reduce_sum(s1);
    s2 = wave_reduce_sum(s2);
    b1 = wave_reduce_sum(b1);
    b2 = wave_reduce_sum(b2);

    __shared__ double red[NWAVES][4];
    int lane = threadIdx.x & 63;
    int wave = threadIdx.x >> 6;
    if (lane == 0) {
        red[wave][0] = s1; red[wave][1] = s2;
        red[wave][2] = b1; red[wave][3] = b2;
    }
    __syncthreads();

    // Waves 1..3 are done; wave 0 publishes + polls once.
    if (threadIdx.x >= 64) return;

    if (threadIdx.x == 0) {
        double t0 = 0, t1 = 0, t2 = 0, t3 = 0;
        #pragma unroll
        for (int w = 0; w < NWAVES; ++w) {
            t0 += red[w][0]; t1 += red[w][1];
            t2 += red[w][2]; t3 += red[w][3];
        }
        u64* p = ws + 8 * (u64)blockIdx.x;
        u64 v0 = d2u(t0), v1 = d2u(t1), v2 = d2u(t2), v3 = d2u(t3);
        astore(&p[0], v0); astore(&p[1], v1);
        astore(&p[2], v2); astore(&p[3], v3);
        astore(&p[4], ~v0); astore(&p[5], ~v1);
        astore(&p[6], ~v2); astore(&p[7], ~v3);
    }
    // vmcnt is per-WAVE: this wave-wide fence covers lane 0's stores, and
    // its agent-scope release semantics push them to the coherence point
    // before the poll loads below are serviced.
    __threadfence();

    // ---- poll ONCE: lane t<20 validates block t's 4 self-checking pairs ----
    bool valid = true;
    double q0 = 0, q1 = 0, q2 = 0, q3 = 0;
    if (threadIdx.x < NBLK) {
        const u64* p = ws + 8 * (u64)threadIdx.x;
        u64 a0 = aload(&p[0]), a1 = aload(&p[1]);
        u64 a2 = aload(&p[2]), a3 = aload(&p[3]);
        u64 c0 = aload(&p[4]), c1 = aload(&p[5]);
        u64 c2 = aload(&p[6]), c3 = aload(&p[7]);
        valid = (c0 == ~a0) & (c1 == ~a1) & (c2 == ~a2) & (c3 == ~a3);
        q0 = u2d(a0); q1 = u2d(a1); q2 = u2d(a2); q3 = u2d(a3);
    }

    if (__all(valid)) {
        // All 20 partials observed -> finalize. The real-time-last publisher
        // always lands here; earlier blocks may too (benign duplicates).
        q0 = wave_reduce_sum(q0);
        q1 = wave_reduce_sum(q1);
        q2 = wave_reduce_sum(q2);
        q3 = wave_reduce_sum(q3);
        if (threadIdx.x == 0) {
            double n = (double)N_ROWS;
            out[0] = (float)(n * q1 - 2.0 * q0 * q2 + n * q3);
        }
    }
}

extern "C" void kernel_launch(void* const* d_in, const int* in_sizes, int n_in,
                              void* d_out, int out_size, void* d_ws, size_t ws_size,
                              hipStream_t stream) {
    const float* A = (const float*)d_in[0];   // [5000,20]
    const float* b = (const float*)d_in[1];   // [5000]
    const float* x = (const float*)d_in[2];   // [20]
    float* out = (float*)d_out;
    u64* ws = (u64*)d_ws;                     // 20 blocks * 8 u64 = 1280 B

    lsq_fused_kernel<<<NBLK, BLKSZ, 0, stream>>>(A, b, x, ws, out);
}